// Round 9
// baseline (1260.535 us; speedup 1.0000x reference)
//
#include <hip/hip_runtime.h>
#include <hip/hip_bf16.h>

#define Hn    89
#define Tn    120
#define RW    16                 // batch rows per wave
#define WPB   4                  // waves per block (256 threads)
#define XPIT  416                // X LDS row pitch bytes (104 f32)
#define XSLOT 7168               // X slot bytes (16*416=6656 + slack for 7th 1KB chunk)
#define HPIT  208                // h scratch row pitch bytes (104 bf16)
#define HSCR  3328               // 16*208
#define ROWB  (Tn*Hn*4)          // 42720 bytes per batch row
#define TSTEP (Hn*4)             // 356
#define OMAX  (RW*ROWB - 16)     // clamp for 16B chunk sources (stay in wave's rows)
#define OEMAX (RW*ROWB - 4)      // clamp for the x[88] scalar load

#define SRZ (-1.44269504f)       // sigmoid pre-scale folded into r/z weights
#define SNN ( 2.88539008f)       // tanh pre-scale folded into n weights

using bf16   = __bf16;
using bf16x4 = __attribute__((ext_vector_type(4))) __bf16;
using bf16x8 = __attribute__((ext_vector_type(8))) __bf16;
typedef __attribute__((ext_vector_type(4))) float f32x4;
typedef __attribute__((ext_vector_type(2))) float f32x2;

typedef const __attribute__((address_space(1))) unsigned int guint;
typedef __attribute__((address_space(3))) unsigned int luint;

__device__ __forceinline__ f32x4 ld4(const float* p) {
  f32x4 v; __builtin_memcpy(&v, p, 16); return v;
}
__device__ __forceinline__ float frcp(float x) { return __builtin_amdgcn_rcpf(x); }
__device__ __forceinline__ float fex2(float x) { return __builtin_amdgcn_exp2f(x); }
__device__ __forceinline__ float fsig(float x) { return frcp(1.f + fex2(-1.44269504f * x)); }

// Barrier-free GRU: each wave owns 16 batch rows for all 120 steps.
// Weights: jt=0..4 (j<80) as 90 persistent register A-frags (360 VGPR, unified
// VGPR/AGPR file); jt=5 (j 80..95) as 18 frags in block-shared LDS.
// h carried as bf16; per-step wave-private LDS round-trip (write C/D-layout
// b64, read back as B-frags) with NO __syncthreads — same-wave DS ordering via
// lgkmcnt. X streamed global->LDS via 7x global_load_lds(16B)/step, 3-slot
// rotation, counted vmcnt(16). Biases ride k=89 columns: X col89:=1.0 patched
// per step (with the separately-loaded real x[88]); h col89:=1.0 forced at the
// jt=5 write. All pads finite; padded weight rows/cols are exactly zero.
__global__ __launch_bounds__(256, 1)
void gru_wave(const float* __restrict__ X,    // [B][T][89]
              const float* __restrict__ Wih,  // [267][89]
              const float* __restrict__ Whh,  // [267][89]
              const float* __restrict__ bih,  // [267]
              const float* __restrict__ bhh,  // [267]
              const float* __restrict__ Wm,   // [32][89]
              const float* __restrict__ bm,   // [32]
              const float* __restrict__ Wo,   // [32]
              const float* __restrict__ bo,   // [1]
              float* __restrict__ Y,          // [B] mscore | [B][32] mmetric
              int Bt)
{
  __shared__ __align__(16) char xraw[WPB * 3 * XSLOT];  // 86016 B
  __shared__ __align__(16) char hraw[WPB * HSCR];       // 13312 B
  __shared__ __align__(16) char wraw[18 * 1024];        // 18432 B (jt=5 frags)

  const int tid  = threadIdx.x;
  const int lane = tid & 63;
  const int wv   = tid >> 6;
  const int l15  = lane & 15;
  const int kg   = lane >> 4;            // 0..3

  // ---- weight frag builder (pre-scaled; k==89 column carries biases) ----
  auto bfrag = [&](int g, int s, int jr, int kt) -> bf16x8 {
    const float sc = (g < 2) ? SRZ : SNN;
    const float* W = s ? Whh : Wih;
    bf16x8 f;
#pragma unroll
    for (int e = 0; e < 8; ++e) {
      const int k = kt * 32 + kg * 8 + e;
      float v = 0.f;
      if (jr < Hn) {
        if (k < Hn) v = sc * W[(size_t)(g * Hn + jr) * Hn + k];
        else if (k == Hn) {     // pairs with X[89]==1 (s=0) or h[89]==1 (s=1)
          if (s == 0) v = (g < 2) ? sc * (bih[g * Hn + jr] + bhh[g * Hn + jr])
                                  : SNN * bih[2 * Hn + jr];
          else        v = (g < 2) ? 0.f : SNN * bhh[2 * Hn + jr];
        }
      }
      f[e] = (bf16)v;
    }
    return f;
  };

  // ---- persistent register weights: jt 0..4 (all rows real, j<80) ----
  bf16x8 Bw[3][2][5][3];
#pragma unroll
  for (int g = 0; g < 3; ++g)
#pragma unroll
    for (int s = 0; s < 2; ++s)
#pragma unroll
      for (int jt = 0; jt < 5; ++jt)
#pragma unroll
        for (int kt = 0; kt < 3; ++kt)
          Bw[g][s][jt][kt] = bfrag(g, s, 16 * jt + l15, kt);

  // ---- jt=5 frags -> block LDS (wave 0 stages; others read per step) ----
  if (wv == 0) {
#pragma unroll
    for (int g = 0; g < 3; ++g)
#pragma unroll
      for (int s = 0; s < 2; ++s)
#pragma unroll
        for (int kt = 0; kt < 3; ++kt) {
          bf16x8 f = bfrag(g, s, 80 + l15, kt);
          *(bf16x8*)(wraw + (size_t)(((g * 2 + s) * 3 + kt) * 1024 + lane * 16)) = f;
        }
  }

  // ---- h scratch init: zeros, col89 = 1.0 ----
  if (lane < 16) {
    char* hr0 = hraw + wv * HSCR + lane * HPIT;
    const f32x4 z4 = {0.f, 0.f, 0.f, 0.f};
#pragma unroll
    for (int cb = 0; cb < 13; ++cb) *(f32x4*)(hr0 + 16 * cb) = z4;
    *(unsigned*)(hr0 + 176) = 0x3F800000u;   // bf16 pair {col88=0, col89=1.0}
  }

  // ---- X staging geometry ----
  const size_t brow0 = (size_t)blockIdx.x * (WPB * RW) + wv * RW;
  const char* xgw = (const char*)X + brow0 * ROWB;
  unsigned off[7];
#pragma unroll
  for (int m = 0; m < 7; ++m) {
    const int idx = 256 * m + 4 * lane;      // f32 index in [16][104] buffer
    int r = idx / 104; if (r > 15) r = 15;   // slack chunk -> clamp row
    const int c = idx % 104;
    const int cs = (c <= 84) ? c : (c == 88 ? 85 : 84);  // finite, in-row src
    off[m] = (unsigned)(r * ROWB + cs * 4);
  }
  const unsigned oe = (unsigned)(lane * ROWB + 88 * 4);  // x[88] (lanes<16)

  auto issue7 = [&](unsigned slot, unsigned tofv) {
#pragma unroll
    for (int m = 0; m < 7; ++m) {
      unsigned o = off[m] + tofv; if (o > OMAX) o = OMAX;
      __builtin_amdgcn_global_load_lds((guint*)(xgw + o),
                                       (luint*)(xraw + slot + 1024 * m), 16, 0, 0);
    }
  };

  __syncthreads();   // wave0's jt5-frag writes visible to all

  // ---- prologue prefetch: slots for t=0,1 + x[88] scalars ----
  unsigned xsA = (unsigned)(wv * 3 * XSLOT);
  unsigned xsB = xsA + XSLOT;
  unsigned xsC = xsA + 2 * XSLOT;
  float xeA = 0.f, xeB = 0.f;
  issue7(xsA, 0);
  if (lane < 16) xeA = *(const float*)(xgw + oe);
  issue7(xsB, TSTEP);
  if (lane < 16) xeB = *(const float*)(xgw + oe + TSTEP);

  // ---- lane-constant bases ----
  const unsigned hbase = (unsigned)(wv * HSCR + l15 * HPIT + 16 * kg);  // B-frag reads
  const unsigned hwb   = (unsigned)(wv * HSCR + l15 * HPIT + 8 * kg);   // C/D b64 writes
  const unsigned xfb   = (unsigned)(l15 * XPIT + 32 * kg);

  bf16x4 hold[6];
  {
    const bf16x4 z = {(bf16)0.f, (bf16)0.f, (bf16)0.f, (bf16)0.f};
#pragma unroll
    for (int jt = 0; jt < 6; ++jt) hold[jt] = z;
  }

  unsigned tof = 2 * TSTEP;
  for (int t = 0; t < Tn; ++t) {
    // issue slot t+2 (uniform body; clamped junk issues at the tail)
    issue7(xsC, tof);
    float xeN = 0.f;
    {
      unsigned o = oe + tof; if (o > OEMAX) o = OEMAX;
      if (lane < 16) xeN = *(const float*)(xgw + o);
    }
    asm volatile("s_waitcnt vmcnt(16)" ::: "memory");   // slot t complete

    // patch consumed slot: col88 = real x[88], col89 = 1.0 (bias column)
    if (lane < 16)
      *(f32x2*)(xraw + xsA + lane * XPIT + 352) = (f32x2){xeA, 1.0f};
    asm volatile("s_waitcnt lgkmcnt(0)" ::: "memory");  // patch + h(t) writes done

    // B-frags: h (bf16 direct), X (f32 -> bf16)
    bf16x8 hf[3], xf[3];
#pragma unroll
    for (int kt = 0; kt < 3; ++kt) {
      hf[kt] = *(const bf16x8*)(hraw + hbase + 64 * kt);
      const f32x4 a = *(const f32x4*)(xraw + xsA + xfb + 128 * kt);
      const f32x4 b = *(const f32x4*)(xraw + xsA + xfb + 128 * kt + 16);
      bf16x8 xv;
#pragma unroll
      for (int e = 0; e < 4; ++e) { xv[e] = (bf16)a[e]; xv[4 + e] = (bf16)b[e]; }
      xf[kt] = xv;
    }

    // gates + h-write for one j-tile (C/D: lane owns j=16jt+4kg+q, row=l15)
    auto gates = [&](int jt, const f32x4& ar, const f32x4& az,
                     const f32x4& ain, const f32x4& ahn, bool m5) {
      bf16x4 wv4;
#pragma unroll
      for (int q = 0; q < 4; ++q) {
        const float r_ = frcp(1.f + fex2(ar[q]));
        const float z_ = frcp(1.f + fex2(az[q]));
        const float s_ = ain[q] + r_ * ahn[q];
        const float n_ = fmaf(-2.f, frcp(1.f + fex2(s_)), 1.f);
        const float hp = (float)hold[jt][q];
        wv4[q] = (bf16)(n_ + z_ * (hp - n_));
      }
      if (m5) {   // j = 80+4kg+q: force j==89 -> 1.0, j>=90 -> 0
        if (kg == 2) { wv4[1] = (bf16)1.0f; wv4[2] = (bf16)0.f; wv4[3] = (bf16)0.f; }
        if (kg == 3) { wv4[0] = (bf16)0.f; wv4[1] = (bf16)0.f;
                       wv4[2] = (bf16)0.f; wv4[3] = (bf16)0.f; }
      }
      hold[jt] = wv4;
      *(bf16x4*)(hraw + hwb + 32 * jt) = wv4;   // h(t+1)[j0..j0+3] @ row l15
    };

    // jt=5 first (LDS weights; reads bounded to this region)
    {
      f32x4 ar = {0,0,0,0}, az = {0,0,0,0}, ain = {0,0,0,0}, ahn = {0,0,0,0};
#pragma unroll
      for (int kt = 0; kt < 3; ++kt) {
        const bf16x8 wri = *(const bf16x8*)(wraw + (0 * 3 + kt) * 1024 + lane * 16);
        const bf16x8 wrh = *(const bf16x8*)(wraw + (1 * 3 + kt) * 1024 + lane * 16);
        const bf16x8 wzi = *(const bf16x8*)(wraw + (2 * 3 + kt) * 1024 + lane * 16);
        const bf16x8 wzh = *(const bf16x8*)(wraw + (3 * 3 + kt) * 1024 + lane * 16);
        const bf16x8 wni = *(const bf16x8*)(wraw + (4 * 3 + kt) * 1024 + lane * 16);
        const bf16x8 wnh = *(const bf16x8*)(wraw + (5 * 3 + kt) * 1024 + lane * 16);
        ar  = __builtin_amdgcn_mfma_f32_16x16x32_bf16(wri, xf[kt], ar, 0, 0, 0);
        ar  = __builtin_amdgcn_mfma_f32_16x16x32_bf16(wrh, hf[kt], ar, 0, 0, 0);
        az  = __builtin_amdgcn_mfma_f32_16x16x32_bf16(wzi, xf[kt], az, 0, 0, 0);
        az  = __builtin_amdgcn_mfma_f32_16x16x32_bf16(wzh, hf[kt], az, 0, 0, 0);
        ain = __builtin_amdgcn_mfma_f32_16x16x32_bf16(wni, xf[kt], ain, 0, 0, 0);
        ahn = __builtin_amdgcn_mfma_f32_16x16x32_bf16(wnh, hf[kt], ahn, 0, 0, 0);
      }
      gates(5, ar, az, ain, ahn, true);
    }
    // jt=0..4 from register weights
#pragma unroll
    for (int jt = 0; jt < 5; ++jt) {
      f32x4 ar = {0,0,0,0}, az = {0,0,0,0}, ain = {0,0,0,0}, ahn = {0,0,0,0};
#pragma unroll
      for (int kt = 0; kt < 3; ++kt) {
        ar  = __builtin_amdgcn_mfma_f32_16x16x32_bf16(Bw[0][0][jt][kt], xf[kt], ar, 0, 0, 0);
        ar  = __builtin_amdgcn_mfma_f32_16x16x32_bf16(Bw[0][1][jt][kt], hf[kt], ar, 0, 0, 0);
        az  = __builtin_amdgcn_mfma_f32_16x16x32_bf16(Bw[1][0][jt][kt], xf[kt], az, 0, 0, 0);
        az  = __builtin_amdgcn_mfma_f32_16x16x32_bf16(Bw[1][1][jt][kt], hf[kt], az, 0, 0, 0);
        ain = __builtin_amdgcn_mfma_f32_16x16x32_bf16(Bw[2][0][jt][kt], xf[kt], ain, 0, 0, 0);
        ahn = __builtin_amdgcn_mfma_f32_16x16x32_bf16(Bw[2][1][jt][kt], hf[kt], ahn, 0, 0, 0);
      }
      gates(jt, ar, az, ain, ahn, false);
    }

    // rotations
    const unsigned xt = xsA; xsA = xsB; xsB = xsC; xsC = xt;
    xeA = xeB; xeB = xeN;
    tof += TSTEP;
  }

  asm volatile("s_waitcnt vmcnt(0)" ::: "memory");   // drain before slot reuse

  // ---- epilogue (wave-private): metric_fc + output_fc ----
  const int c  = lane & 31;
  const int rg = lane >> 5;
  const char* hscr_w = hraw + wv * HSCR;
  char* mlb = xraw + wv * 3 * XSLOT;                 // reuse slot0: [16][32] f32
  const float* wrow = Wm + c * Hn;
  float acc[8];
#pragma unroll
  for (int i = 0; i < 8; ++i) acc[i] = bm[c];
#pragma unroll
  for (int cb = 0; cb < 11; ++cb) {
    const f32x4 wa = ld4(wrow + cb * 8);
    const f32x4 wb = ld4(wrow + cb * 8 + 4);
#pragma unroll
    for (int i = 0; i < 8; ++i) {
      const bf16x8 hv = *(const bf16x8*)(hscr_w + (rg * 8 + i) * HPIT + cb * 16);
      float a0 = acc[i];
      a0 = fmaf((float)hv[0], wa[0], a0); a0 = fmaf((float)hv[1], wa[1], a0);
      a0 = fmaf((float)hv[2], wa[2], a0); a0 = fmaf((float)hv[3], wa[3], a0);
      a0 = fmaf((float)hv[4], wb[0], a0); a0 = fmaf((float)hv[5], wb[1], a0);
      a0 = fmaf((float)hv[6], wb[2], a0); a0 = fmaf((float)hv[7], wb[3], a0);
      acc[i] = a0;
    }
  }
  const float w88 = wrow[88];
#pragma unroll
  for (int i = 0; i < 8; ++i) {
    const int r = rg * 8 + i;
    const float h88 = (float)*(const bf16*)(hscr_w + r * HPIT + 176);
    const float mv = fsig(fmaf(h88, w88, acc[i]));
    Y[(size_t)Bt + (brow0 + r) * 32 + c] = mv;       // out_mmetric
    *(float*)(mlb + r * 128 + c * 4) = mv;
  }
  asm volatile("s_waitcnt lgkmcnt(0)" ::: "memory");
  if (lane < 16) {
    float a2 = bo[0];
#pragma unroll
    for (int cb = 0; cb < 8; ++cb) {
      const f32x4 m4 = *(const f32x4*)(mlb + lane * 128 + cb * 16);
      const f32x4 w4 = ld4(Wo + cb * 4);
      a2 = fmaf(m4[0], w4[0], a2); a2 = fmaf(m4[1], w4[1], a2);
      a2 = fmaf(m4[2], w4[2], a2); a2 = fmaf(m4[3], w4[3], a2);
    }
    Y[brow0 + lane] = fsig(a2);                      // out_mscore
  }
}

extern "C" void kernel_launch(void* const* d_in, const int* in_sizes, int n_in,
                              void* d_out, int out_size, void* d_ws, size_t ws_size,
                              hipStream_t stream) {
  const float* X   = (const float*)d_in[0];
  const float* Wih = (const float*)d_in[1];
  const float* Whh = (const float*)d_in[2];
  const float* bih = (const float*)d_in[3];
  const float* bhh = (const float*)d_in[4];
  const float* Wm  = (const float*)d_in[5];
  const float* bm  = (const float*)d_in[6];
  const float* Wo  = (const float*)d_in[7];
  const float* bo  = (const float*)d_in[8];

  const int B = in_sizes[0] / (Tn * Hn);   // 32768
  dim3 grid(B / (WPB * RW)), block(WPB * 64);
  gru_wave<<<grid, block, 0, stream>>>(X, Wih, Whh, bih, bhh, Wm, bm, Wo, bo,
                                       (float*)d_out, B);
}